// Round 1
// baseline (431.496 us; speedup 1.0000x reference)
//
#include <hip/hip_runtime.h>
#include <hip/hip_bf16.h>
#include <math.h>

// Problem constants (fixed by the reference)
//   N=4, L=1024, D=1024, H=16, HD=64, HIST=128, SCALE=32
// Faithful-bug structure: attention[n,l,h,d] = (sum_q scores[n,h,q,l]) * v[n,l,h,d]
// => only column sums w[n,h,l] of the softmax matrix are needed.
// Energy trick: q_p . k_p = xq^T (Wq^T Wk / 32) xk  with M = Wq^T Wk / 32 (64x64).

// ---------------------------------------------------------------------------
// K0: M[e][f] = (1/32) * sum_d Wq[d][e] * Wk[d][f]
// ---------------------------------------------------------------------------
__global__ __launch_bounds__(256) void kM(const float* __restrict__ Wq,
                                          const float* __restrict__ Wk,
                                          float* __restrict__ M) {
    int idx = blockIdx.x * 256 + threadIdx.x;   // 4096 total (grid 16)
    int e = idx >> 6, f = idx & 63;
    float s = 0.f;
#pragma unroll 8
    for (int d = 0; d < 64; ++d) s = fmaf(Wq[d * 64 + e], Wk[d * 64 + f], s);
    M[idx] = s * (1.0f / 32.0f);
}

// ---------------------------------------------------------------------------
// K1: w[n,h,l] = sum_q softmax-band scores column sums.
// One block = 64 query rows of one (n,h). Keys span 191 slots (l = t0-127+c).
// Energy tile 64x192 computed as (yq 64x64) x (xk 64x192), yq = xq*M (bf16 LDS),
// register tile 4 rows x 12 keys per thread (16x16 thread grid).
// ---------------------------------------------------------------------------
__global__ __launch_bounds__(256) void k_w(const float* __restrict__ query,
                                           const float* __restrict__ keys,
                                           const float* __restrict__ Mm,
                                           float* __restrict__ w) {
    __shared__ float xk[64 * 196];            // [f][c] stride 196 (phase1: xq_t stride 65)
    __shared__ unsigned short yqb[64 * 66];   // [f][r] bf16, stride 66
    __shared__ float wloc[192];

    const int tid  = threadIdx.x;
    const int b    = blockIdx.x;
    const int tile = b & 15;        // L/64 = 16 row tiles
    const int nh   = b >> 4;
    const int h    = nh & 15;
    const int n    = nh >> 4;
    const int t0   = tile * 64;

    if (tid < 192) wloc[tid] = 0.f;

    // phase 1: stage xq_t[e][r] = query[n, t0+r, h*64+e]  (stride 65: conflict-free)
    {
        const float* qbase = query + ((size_t)(n * 1024 + t0)) * 1024 + h * 64;
        for (int idx = tid; idx < 4096; idx += 256) {
            int e = idx & 63, r = idx >> 6;
            xk[e * 65 + r] = qbase[(size_t)r * 1024 + e];
        }
    }
    __syncthreads();

    // phase 2: yq[r][f] = sum_e xq[r][e] * M[e][f]  -> bf16 LDS [f][r]
    for (int idx = tid; idx < 4096; idx += 256) {
        int f = idx & 63, r = idx >> 6;
        float s = 0.f;
#pragma unroll 8
        for (int e = 0; e < 64; ++e)
            s = fmaf(xk[e * 65 + r], Mm[e * 64 + f], s);
        unsigned u = __float_as_uint(s);
        u += 0x7FFFu + ((u >> 16) & 1u);      // round-to-nearest-even bf16
        yqb[f * 66 + r] = (unsigned short)(u >> 16);
    }
    __syncthreads();

    // phase 3: stage keys xk[f][c], c=0..191 <-> l = t0-127+c
    {
        const float* kbase = keys + (size_t)n * 1024 * 1024 + h * 64;
        for (int idx = tid; idx < 64 * 192; idx += 256) {
            int f = idx & 63, c = idx >> 6;
            int l = t0 - 127 + c;
            float v = 0.f;
            if (l >= 0 && l < 1024) v = kbase[(size_t)l * 1024 + f];
            xk[f * 196 + c] = v;
        }
    }
    __syncthreads();

    // phase 4: energy tile, 4 rows x 12 keys per thread
    const int ry = tid >> 4;     // 0..15 -> rows ry*4..+3
    const int cx = tid & 15;     // 0..15 -> cols cx*12..+11
    const int r0 = ry * 4;
    const int c0 = cx * 12;

    float acc[4][12];
#pragma unroll
    for (int i = 0; i < 4; ++i)
#pragma unroll
        for (int j = 0; j < 12; ++j) acc[i][j] = 0.f;

    for (int k = 0; k < 64; ++k) {
        uint2 uq = *reinterpret_cast<const uint2*>(&yqb[k * 66 + r0]);
        float qq[4];
        qq[0] = __uint_as_float(uq.x << 16);
        qq[1] = __uint_as_float(uq.x & 0xFFFF0000u);
        qq[2] = __uint_as_float(uq.y << 16);
        qq[3] = __uint_as_float(uq.y & 0xFFFF0000u);
        const float* kp = &xk[k * 196 + c0];
        float4 kv0 = *reinterpret_cast<const float4*>(kp);
        float4 kv1 = *reinterpret_cast<const float4*>(kp + 4);
        float4 kv2 = *reinterpret_cast<const float4*>(kp + 8);
        float kk[12] = {kv0.x, kv0.y, kv0.z, kv0.w,
                        kv1.x, kv1.y, kv1.z, kv1.w,
                        kv2.x, kv2.y, kv2.z, kv2.w};
#pragma unroll
        for (int i = 0; i < 4; ++i)
#pragma unroll
            for (int j = 0; j < 12; ++j)
                acc[i][j] = fmaf(qq[i], kk[j], acc[i][j]);
    }

    // softmax rows (logits tiny -> exp without max-sub is exact enough),
    // then column-sum contributions into wloc
#pragma unroll
    for (int i = 0; i < 4; ++i) {
        const int r_loc = r0 + i;
        float rs = 0.f;
#pragma unroll
        for (int j = 0; j < 12; ++j) {
            int c = c0 + j;
            bool valid = (c >= r_loc) && (c <= r_loc + 127) && (c + t0 >= 127);
            float e = valid ? __expf(acc[i][j]) : 0.f;
            acc[i][j] = e;
            rs += e;
        }
#pragma unroll
        for (int m = 1; m < 16; m <<= 1) rs += __shfl_xor(rs, m);
        float inv = 1.0f / rs;   // diagonal key always valid -> rs > 0
#pragma unroll
        for (int j = 0; j < 12; ++j) acc[i][j] *= inv;
    }
#pragma unroll
    for (int j = 0; j < 12; ++j) {
        float s = acc[0][j] + acc[1][j] + acc[2][j] + acc[3][j];
        atomicAdd(&wloc[c0 + j], s);
    }
    __syncthreads();

    for (int c = tid; c < 192; c += 256) {
        int l = t0 - 127 + c;
        if (l >= 0 && l < 1024) {
            float v = wloc[c];
            atomicAdd(&w[((size_t)(n * 16 + h)) * 1024 + l], v);
        }
    }
}

// ---------------------------------------------------------------------------
// K2: ap[row][d] = w_scale(row) * sum_e values_row[e] * Wv[d][e]
// values viewed as (N*L*H, 64) row-major (head rows are contiguous).
// Block = 128 rows; thread tile 8 rows x 4 cols.
// ---------------------------------------------------------------------------
__global__ __launch_bounds__(256) void k_ap(const float* __restrict__ values,
                                            const float* __restrict__ Wv,
                                            const float* __restrict__ w,
                                            float* __restrict__ ap) {
    __shared__ float At[64 * 132];   // [e][r], stride 132 (b128-aligned reads)
    __shared__ float WvT[64 * 68];   // [e][d], stride 68

    const int tid = threadIdx.x;
    const long R0 = (long)blockIdx.x * 128;

    for (int idx = tid; idx < 4096; idx += 256) {
        int e = idx & 63, d = idx >> 6;
        WvT[e * 68 + d] = Wv[d * 64 + e];
    }
    {
        const float* vbase = values + R0 * 64;
        for (int idx = tid; idx < 8192; idx += 256) {
            int e = idx & 63, r = idx >> 6;
            At[e * 132 + r] = vbase[(size_t)r * 64 + e];
        }
    }
    __syncthreads();

    const int ry = tid >> 4;   // rows ry*8..+7
    const int cx = tid & 15;   // cols cx*4..+3
    float acc[8][4];
#pragma unroll
    for (int i = 0; i < 8; ++i)
#pragma unroll
        for (int j = 0; j < 4; ++j) acc[i][j] = 0.f;

    for (int k = 0; k < 64; ++k) {
        float4 a0 = *reinterpret_cast<const float4*>(&At[k * 132 + ry * 8]);
        float4 a1 = *reinterpret_cast<const float4*>(&At[k * 132 + ry * 8 + 4]);
        float4 bb = *reinterpret_cast<const float4*>(&WvT[k * 68 + cx * 4]);
        float av[8] = {a0.x, a0.y, a0.z, a0.w, a1.x, a1.y, a1.z, a1.w};
        float bv[4] = {bb.x, bb.y, bb.z, bb.w};
#pragma unroll
        for (int i = 0; i < 8; ++i)
#pragma unroll
            for (int j = 0; j < 4; ++j)
                acc[i][j] = fmaf(av[i], bv[j], acc[i][j]);
    }

#pragma unroll
    for (int i = 0; i < 8; ++i) {
        long row = R0 + ry * 8 + i;
        int hh = (int)(row & 15);
        int ll = (int)((row >> 4) & 1023);
        int nn = (int)(row >> 14);
        float wf = w[((size_t)(nn * 16 + hh) << 10) + ll];
        float4 o = make_float4(acc[i][0] * wf, acc[i][1] * wf,
                               acc[i][2] * wf, acc[i][3] * wf);
        *reinterpret_cast<float4*>(&ap[row * 64 + cx * 4]) = o;
    }
}

// ---------------------------------------------------------------------------
// K3: out = ap (4096x1024) @ Wo^T (Wo row-major 1024x1024) + bo
// 128x128 block tile, BK=16, thread tile 8 rows x 8 spread cols.
// ---------------------------------------------------------------------------
__global__ __launch_bounds__(256) void k_out(const float* __restrict__ ap,
                                             const float* __restrict__ Wo,
                                             const float* __restrict__ bo,
                                             float* __restrict__ out) {
    __shared__ float As[16 * 132];   // [k][m]
    __shared__ float Bs[16 * 132];   // [k][jc]
    const int tid = threadIdx.x;
    const int bx = blockIdx.x & 7;    // 8 col tiles
    const int by = blockIdx.x >> 3;   // 32 row tiles
    const int ty = tid >> 4, tx = tid & 15;

    const long arow0 = (long)by * 128;
    const int  bcol0 = bx * 128;

    float acc[8][8];
#pragma unroll
    for (int i = 0; i < 8; ++i)
#pragma unroll
        for (int j = 0; j < 8; ++j) acc[i][j] = 0.f;

    for (int kt = 0; kt < 64; ++kt) {
        const int k0 = kt * 16;
#pragma unroll
        for (int i = 0; i < 2; ++i) {
            int idx = tid + i * 256;          // 0..511
            int m = idx >> 2, kq = idx & 3;
            float4 v = *reinterpret_cast<const float4*>(
                &ap[(arow0 + m) * 1024 + k0 + kq * 4]);
            As[(kq * 4 + 0) * 132 + m] = v.x;
            As[(kq * 4 + 1) * 132 + m] = v.y;
            As[(kq * 4 + 2) * 132 + m] = v.z;
            As[(kq * 4 + 3) * 132 + m] = v.w;
        }
#pragma unroll
        for (int i = 0; i < 2; ++i) {
            int idx = tid + i * 256;
            int jc = idx >> 2, kq = idx & 3;
            float4 v = *reinterpret_cast<const float4*>(
                &Wo[(size_t)(bcol0 + jc) * 1024 + k0 + kq * 4]);
            Bs[(kq * 4 + 0) * 132 + jc] = v.x;
            Bs[(kq * 4 + 1) * 132 + jc] = v.y;
            Bs[(kq * 4 + 2) * 132 + jc] = v.z;
            Bs[(kq * 4 + 3) * 132 + jc] = v.w;
        }
        __syncthreads();
#pragma unroll
        for (int k = 0; k < 16; ++k) {
            float4 a0 = *reinterpret_cast<const float4*>(&As[k * 132 + ty * 8]);
            float4 a1 = *reinterpret_cast<const float4*>(&As[k * 132 + ty * 8 + 4]);
            float av[8] = {a0.x, a0.y, a0.z, a0.w, a1.x, a1.y, a1.z, a1.w};
            float bv[8];
#pragma unroll
            for (int j = 0; j < 8; ++j) bv[j] = Bs[k * 132 + tx + 16 * j];
#pragma unroll
            for (int i = 0; i < 8; ++i)
#pragma unroll
                for (int j = 0; j < 8; ++j)
                    acc[i][j] = fmaf(av[i], bv[j], acc[i][j]);
        }
        __syncthreads();
    }

    float bb[8];
#pragma unroll
    for (int j = 0; j < 8; ++j) bb[j] = bo[bcol0 + tx + 16 * j];
#pragma unroll
    for (int i = 0; i < 8; ++i) {
        long r = arow0 + ty * 8 + i;
        float* op = out + r * 1024 + bcol0;
#pragma unroll
        for (int j = 0; j < 8; ++j) op[tx + 16 * j] = acc[i][j] + bb[j];
    }
}

// ---------------------------------------------------------------------------
extern "C" void kernel_launch(void* const* d_in, const int* in_sizes, int n_in,
                              void* d_out, int out_size, void* d_ws, size_t ws_size,
                              hipStream_t stream) {
    // setup_inputs order: values, keys, query, mask(ignored), Wv, Wk, Wq, Wo, bo
    const float* values = (const float*)d_in[0];
    const float* keys   = (const float*)d_in[1];
    const float* query  = (const float*)d_in[2];
    const float* Wv     = (const float*)d_in[4];
    const float* Wk     = (const float*)d_in[5];
    const float* Wq     = (const float*)d_in[6];
    const float* Wo     = (const float*)d_in[7];
    const float* bo     = (const float*)d_in[8];
    float* out = (float*)d_out;

    float* Mws = (float*)d_ws;            // 4096 floats
    float* w   = Mws + 4096;              // 65536 floats
    float* ap  = w + 65536;               // 4,194,304 floats

    hipMemsetAsync(w, 0, 65536 * sizeof(float), stream);
    kM<<<16, 256, 0, stream>>>(Wq, Wk, Mws);
    k_w<<<1024, 256, 0, stream>>>(query, keys, Mws, w);
    k_ap<<<512, 256, 0, stream>>>(values, Wv, w, ap);
    k_out<<<256, 256, 0, stream>>>(ap, Wo, bo, out);
}

// Round 2
// 259.170 us; speedup vs baseline: 1.6649x; 1.6649x over previous
//
#include <hip/hip_runtime.h>
#include <hip/hip_bf16.h>
#include <math.h>

// Problem constants (fixed by the reference)
//   N=4, L=1024, D=1024, H=16, HD=64, HIST=128, SCALE=32
// Faithful-bug structure: attention[n,l,h,d] = (sum_q scores[n,h,q,l]) * v[n,l,h,d]
// => only column sums w[n,h,l] of the softmax matrix are needed.
// Energy trick: q_p . k_p = xq^T (Wq^T Wk / 32) xk  with M = Wq^T Wk / 32 (64x64).
// Round 2: k_out rewritten as bf16 MFMA GEMM (m97 structure); ap/Wo in bf16.

__device__ __forceinline__ unsigned short f2bf(float x) {
    unsigned u = __float_as_uint(x);
    u += 0x7FFFu + ((u >> 16) & 1u);      // round-to-nearest-even
    return (unsigned short)(u >> 16);
}

// ---------------------------------------------------------------------------
// K0: M[e][f] = (1/32) * sum_d Wq[d][e] * Wk[d][f]
// ---------------------------------------------------------------------------
__global__ __launch_bounds__(256) void kM(const float* __restrict__ Wq,
                                          const float* __restrict__ Wk,
                                          float* __restrict__ M) {
    int idx = blockIdx.x * 256 + threadIdx.x;   // 4096 total (grid 16)
    int e = idx >> 6, f = idx & 63;
    float s = 0.f;
#pragma unroll 8
    for (int d = 0; d < 64; ++d) s = fmaf(Wq[d * 64 + e], Wk[d * 64 + f], s);
    M[idx] = s * (1.0f / 32.0f);
}

// ---------------------------------------------------------------------------
// K0b: Wo (1024x1024 f32) -> bf16
// ---------------------------------------------------------------------------
__global__ __launch_bounds__(256) void k_cw(const float4* __restrict__ Wo4,
                                            ushort4* __restrict__ Wob4) {
    int idx = blockIdx.x * 256 + threadIdx.x;   // 262144 (grid 1024)
    float4 v = Wo4[idx];
    ushort4 o;
    o.x = f2bf(v.x); o.y = f2bf(v.y); o.z = f2bf(v.z); o.w = f2bf(v.w);
    Wob4[idx] = o;
}

// ---------------------------------------------------------------------------
// K1: w[n,h,l] = sum_q softmax-band scores column sums.
// One block = 64 query rows of one (n,h). Keys span 191 slots (l = t0-127+c).
// ---------------------------------------------------------------------------
__global__ __launch_bounds__(256) void k_w(const float* __restrict__ query,
                                           const float* __restrict__ keys,
                                           const float* __restrict__ Mm,
                                           float* __restrict__ w) {
    __shared__ float xk[64 * 196];            // [f][c] stride 196 (phase1: xq_t stride 65)
    __shared__ unsigned short yqb[64 * 66];   // [f][r] bf16, stride 66
    __shared__ float wloc[192];

    const int tid  = threadIdx.x;
    const int b    = blockIdx.x;
    const int tile = b & 15;        // L/64 = 16 row tiles
    const int nh   = b >> 4;
    const int h    = nh & 15;
    const int n    = nh >> 4;
    const int t0   = tile * 64;

    if (tid < 192) wloc[tid] = 0.f;

    // phase 1: stage xq_t[e][r] = query[n, t0+r, h*64+e]  (stride 65: conflict-free)
    {
        const float* qbase = query + ((size_t)(n * 1024 + t0)) * 1024 + h * 64;
        for (int idx = tid; idx < 4096; idx += 256) {
            int e = idx & 63, r = idx >> 6;
            xk[e * 65 + r] = qbase[(size_t)r * 1024 + e];
        }
    }
    __syncthreads();

    // phase 2: yq[r][f] = sum_e xq[r][e] * M[e][f]  -> bf16 LDS [f][r]
    for (int idx = tid; idx < 4096; idx += 256) {
        int f = idx & 63, r = idx >> 6;
        float s = 0.f;
#pragma unroll 8
        for (int e = 0; e < 64; ++e)
            s = fmaf(xk[e * 65 + r], Mm[e * 64 + f], s);
        yqb[f * 66 + r] = f2bf(s);
    }
    __syncthreads();

    // phase 3: stage keys xk[f][c], c=0..191 <-> l = t0-127+c
    {
        const float* kbase = keys + (size_t)n * 1024 * 1024 + h * 64;
        for (int idx = tid; idx < 64 * 192; idx += 256) {
            int f = idx & 63, c = idx >> 6;
            int l = t0 - 127 + c;
            float v = 0.f;
            if (l >= 0 && l < 1024) v = kbase[(size_t)l * 1024 + f];
            xk[f * 196 + c] = v;
        }
    }
    __syncthreads();

    // phase 4: energy tile, 4 rows x 12 keys per thread
    const int ry = tid >> 4;     // 0..15 -> rows ry*4..+3
    const int cx = tid & 15;     // 0..15 -> cols cx*12..+11
    const int r0 = ry * 4;
    const int c0 = cx * 12;

    float acc[4][12];
#pragma unroll
    for (int i = 0; i < 4; ++i)
#pragma unroll
        for (int j = 0; j < 12; ++j) acc[i][j] = 0.f;

    for (int k = 0; k < 64; ++k) {
        uint2 uq = *reinterpret_cast<const uint2*>(&yqb[k * 66 + r0]);
        float qq[4];
        qq[0] = __uint_as_float(uq.x << 16);
        qq[1] = __uint_as_float(uq.x & 0xFFFF0000u);
        qq[2] = __uint_as_float(uq.y << 16);
        qq[3] = __uint_as_float(uq.y & 0xFFFF0000u);
        const float* kp = &xk[k * 196 + c0];
        float4 kv0 = *reinterpret_cast<const float4*>(kp);
        float4 kv1 = *reinterpret_cast<const float4*>(kp + 4);
        float4 kv2 = *reinterpret_cast<const float4*>(kp + 8);
        float kk[12] = {kv0.x, kv0.y, kv0.z, kv0.w,
                        kv1.x, kv1.y, kv1.z, kv1.w,
                        kv2.x, kv2.y, kv2.z, kv2.w};
#pragma unroll
        for (int i = 0; i < 4; ++i)
#pragma unroll
            for (int j = 0; j < 12; ++j)
                acc[i][j] = fmaf(qq[i], kk[j], acc[i][j]);
    }

    // softmax rows (logits tiny -> exp without max-sub is exact), column sums
#pragma unroll
    for (int i = 0; i < 4; ++i) {
        const int r_loc = r0 + i;
        float rs = 0.f;
#pragma unroll
        for (int j = 0; j < 12; ++j) {
            int c = c0 + j;
            bool valid = (c >= r_loc) && (c <= r_loc + 127) && (c + t0 >= 127);
            float e = valid ? __expf(acc[i][j]) : 0.f;
            acc[i][j] = e;
            rs += e;
        }
#pragma unroll
        for (int m = 1; m < 16; m <<= 1) rs += __shfl_xor(rs, m);
        float inv = 1.0f / rs;   // diagonal key always valid -> rs > 0
#pragma unroll
        for (int j = 0; j < 12; ++j) acc[i][j] *= inv;
    }
#pragma unroll
    for (int j = 0; j < 12; ++j) {
        float s = acc[0][j] + acc[1][j] + acc[2][j] + acc[3][j];
        atomicAdd(&wloc[c0 + j], s);
    }
    __syncthreads();

    for (int c = tid; c < 192; c += 256) {
        int l = t0 - 127 + c;
        if (l >= 0 && l < 1024) {
            float v = wloc[c];
            atomicAdd(&w[((size_t)(n * 16 + h)) * 1024 + l], v);
        }
    }
}

// ---------------------------------------------------------------------------
// K2: ap[row][d] = w_scale(row) * sum_e values_row[e] * Wv[d][e]  -> bf16
// values viewed as (N*L*H, 64) row-major. Block = 128 rows; tile 8x4/thread.
// ---------------------------------------------------------------------------
__global__ __launch_bounds__(256) void k_ap(const float* __restrict__ values,
                                            const float* __restrict__ Wv,
                                            const float* __restrict__ w,
                                            unsigned short* __restrict__ apb) {
    __shared__ float At[64 * 132];   // [e][r], stride 132
    __shared__ float WvT[64 * 68];   // [e][d], stride 68

    const int tid = threadIdx.x;
    const long R0 = (long)blockIdx.x * 128;

    for (int idx = tid; idx < 4096; idx += 256) {
        int e = idx & 63, d = idx >> 6;
        WvT[e * 68 + d] = Wv[d * 64 + e];
    }
    {
        const float* vbase = values + R0 * 64;
        for (int idx = tid; idx < 8192; idx += 256) {
            int e = idx & 63, r = idx >> 6;
            At[e * 132 + r] = vbase[(size_t)r * 64 + e];
        }
    }
    __syncthreads();

    const int ry = tid >> 4;   // rows ry*8..+7
    const int cx = tid & 15;   // cols cx*4..+3
    float acc[8][4];
#pragma unroll
    for (int i = 0; i < 8; ++i)
#pragma unroll
        for (int j = 0; j < 4; ++j) acc[i][j] = 0.f;

    for (int k = 0; k < 64; ++k) {
        float4 a0 = *reinterpret_cast<const float4*>(&At[k * 132 + ry * 8]);
        float4 a1 = *reinterpret_cast<const float4*>(&At[k * 132 + ry * 8 + 4]);
        float4 bb = *reinterpret_cast<const float4*>(&WvT[k * 68 + cx * 4]);
        float av[8] = {a0.x, a0.y, a0.z, a0.w, a1.x, a1.y, a1.z, a1.w};
        float bv[4] = {bb.x, bb.y, bb.z, bb.w};
#pragma unroll
        for (int i = 0; i < 8; ++i)
#pragma unroll
            for (int j = 0; j < 4; ++j)
                acc[i][j] = fmaf(av[i], bv[j], acc[i][j]);
    }

#pragma unroll
    for (int i = 0; i < 8; ++i) {
        long row = R0 + ry * 8 + i;
        int hh = (int)(row & 15);
        int ll = (int)((row >> 4) & 1023);
        int nn = (int)(row >> 14);
        float wf = w[((size_t)(nn * 16 + hh) << 10) + ll];
        ushort4 o;
        o.x = f2bf(acc[i][0] * wf);
        o.y = f2bf(acc[i][1] * wf);
        o.z = f2bf(acc[i][2] * wf);
        o.w = f2bf(acc[i][3] * wf);
        *reinterpret_cast<ushort4*>(&apb[row * 64 + cx * 4]) = o;
    }
}

// ---------------------------------------------------------------------------
// K3: out = ap (4096x1024 bf16) @ Wo^T (bf16) + bo, f32 out.
// m97 structure: 128x128 tile, BK=32, global_load_lds(16B), 4 waves x (64x64),
// mfma_f32_16x16x32_bf16 4x4 per wave. Grid 256 blocks.
// ---------------------------------------------------------------------------
__global__ __launch_bounds__(256) void k_out_mfma(
    const unsigned short* __restrict__ apb,   // 4096x1024 bf16
    const unsigned short* __restrict__ wob,   // 1024x1024 bf16 (row-major Wo)
    const float* __restrict__ bo,
    float* __restrict__ out) {
    using short8 = __attribute__((ext_vector_type(8))) short;
    using f32x4  = __attribute__((ext_vector_type(4))) float;

    __shared__ unsigned short As[128 * 32];   // [m][k] row-major, no pad
    __shared__ unsigned short Bs[128 * 32];   // [n][k]

    const int tid  = threadIdx.x;
    const int wv   = tid >> 6;     // wave 0..3
    const int lane = tid & 63;
    const int wy   = wv >> 1, wx = wv & 1;

    const int bx = blockIdx.x & 7;    // 8 col tiles
    const int by = blockIdx.x >> 3;   // 32 row tiles
    const long arow0 = (long)by * 128;
    const int  bcol0 = bx * 128;

    f32x4 acc[4][4];
#pragma unroll
    for (int mi = 0; mi < 4; ++mi)
#pragma unroll
        for (int ni = 0; ni < 4; ++ni) acc[mi][ni] = f32x4{0.f, 0.f, 0.f, 0.f};

    // staging map: issue i, thread tid -> LDS 16B slot (i*256+tid)
    //   row = i*64 + (tid>>2), k-offset = (tid&3)*8 elems
    const int r0s = tid >> 2;
    const int kks = (tid & 3) * 8;

    for (int kt = 0; kt < 32; ++kt) {
        const int k0 = kt * 32;
#pragma unroll
        for (int i = 0; i < 2; ++i) {
            const unsigned short* g =
                apb + (arow0 + i * 64 + r0s) * 1024 + k0 + kks;
            __builtin_amdgcn_global_load_lds(
                (const __attribute__((address_space(1))) unsigned int*)g,
                (__attribute__((address_space(3))) unsigned int*)&As[i * 2048 + wv * 512],
                16, 0, 0);
        }
#pragma unroll
        for (int i = 0; i < 2; ++i) {
            const unsigned short* g =
                wob + (size_t)(bcol0 + i * 64 + r0s) * 1024 + k0 + kks;
            __builtin_amdgcn_global_load_lds(
                (const __attribute__((address_space(1))) unsigned int*)g,
                (__attribute__((address_space(3))) unsigned int*)&Bs[i * 2048 + wv * 512],
                16, 0, 0);
        }
        __syncthreads();

        const int koff = (lane >> 4) * 8;
        const int rA = wy * 64 + (lane & 15);
        const int rB = wx * 64 + (lane & 15);
        short8 af[4], bf[4];
#pragma unroll
        for (int mi = 0; mi < 4; ++mi)
            af[mi] = *reinterpret_cast<const short8*>(&As[(rA + mi * 16) * 32 + koff]);
#pragma unroll
        for (int ni = 0; ni < 4; ++ni)
            bf[ni] = *reinterpret_cast<const short8*>(&Bs[(rB + ni * 16) * 32 + koff]);
#pragma unroll
        for (int mi = 0; mi < 4; ++mi)
#pragma unroll
            for (int ni = 0; ni < 4; ++ni)
                acc[mi][ni] = __builtin_amdgcn_mfma_f32_16x16x32_bf16(
                    af[mi], bf[ni], acc[mi][ni], 0, 0, 0);
        __syncthreads();
    }

    // epilogue: D layout col=lane&15, row=(lane>>4)*4+reg
    const int colb = bcol0 + wx * 64 + (lane & 15);
    const int rowb = (int)arow0 + wy * 64 + (lane >> 4) * 4;
#pragma unroll
    for (int ni = 0; ni < 4; ++ni) {
        const int col = colb + ni * 16;
        const float bias = bo[col];
#pragma unroll
        for (int mi = 0; mi < 4; ++mi) {
            const int row = rowb + mi * 16;
#pragma unroll
            for (int r = 0; r < 4; ++r)
                out[(size_t)(row + r) * 1024 + col] = acc[mi][ni][r] + bias;
        }
    }
}

// ---------------------------------------------------------------------------
extern "C" void kernel_launch(void* const* d_in, const int* in_sizes, int n_in,
                              void* d_out, int out_size, void* d_ws, size_t ws_size,
                              hipStream_t stream) {
    // setup_inputs order: values, keys, query, mask(ignored), Wv, Wk, Wq, Wo, bo
    const float* values = (const float*)d_in[0];
    const float* keys   = (const float*)d_in[1];
    const float* query  = (const float*)d_in[2];
    const float* Wv     = (const float*)d_in[4];
    const float* Wk     = (const float*)d_in[5];
    const float* Wq     = (const float*)d_in[6];
    const float* Wo     = (const float*)d_in[7];
    const float* bo     = (const float*)d_in[8];
    float* out = (float*)d_out;

    float* Mws = (float*)d_ws;                          // 4096 f32
    float* w   = Mws + 4096;                            // 65536 f32
    unsigned short* apb = (unsigned short*)(w + 65536); // 4096*1024 bf16
    unsigned short* wob = apb + 4096 * 1024;            // 1024*1024 bf16

    hipMemsetAsync(w, 0, 65536 * sizeof(float), stream);
    kM<<<16, 256, 0, stream>>>(Wq, Wk, Mws);
    k_cw<<<1024, 256, 0, stream>>>((const float4*)Wo, (ushort4*)wob);
    k_w<<<1024, 256, 0, stream>>>(query, keys, Mws, w);
    k_ap<<<512, 256, 0, stream>>>(values, Wv, w, apb);
    k_out_mfma<<<256, 256, 0, stream>>>(apb, wob, bo, out);
}

// Round 4
// 169.657 us; speedup vs baseline: 2.5433x; 1.5276x over previous
//
#include <hip/hip_runtime.h>
#include <hip/hip_bf16.h>
#include <math.h>

// Problem constants: N=4, L=1024, D=1024, H=16, HD=64, HIST=128, SCALE=32
// Faithful-bug structure: attention[n,l,h,d] = (sum_q scores[n,h,q,l]) * v[n,l,h,d]
// => only column sums w[n,h,l] of softmax needed.
// Energy trick: q_p . k_p = xq^T (Wq^T Wk / 32) xk, M = Wq^T Wk / 32 (64x64).
// Round 4: round-3 failure diagnosed as WORKSPACE OVERFLOW (19.2MB > ws_size;
// round 1 proved only >=17.1MB). Fix: fuse yq MFMA into k_w2f (yq lives in
// LDS only), keys gathered by k_kb, apb overlays kbp. Peak ws = 10.77MB
// (below round-2-proven footprint).

using short8 = __attribute__((ext_vector_type(8))) short;
using f32x4  = __attribute__((ext_vector_type(4))) float;

__device__ __forceinline__ unsigned short f2bf(float x) {
    unsigned u = __float_as_uint(x);
    u += 0x7FFFu + ((u >> 16) & 1u);      // round-to-nearest-even
    return (unsigned short)(u >> 16);
}

// ---------------------------------------------------------------------------
// K0: M[e][f] = (1/32) * sum_d Wq[d][e] * Wk[d][f]; Wvb = bf16(Wv)
// ---------------------------------------------------------------------------
__global__ __launch_bounds__(256) void kM2(const float* __restrict__ Wq,
                                           const float* __restrict__ Wk,
                                           const float* __restrict__ Wv,
                                           float* __restrict__ M,
                                           unsigned short* __restrict__ Wvb) {
    int idx = blockIdx.x * 256 + threadIdx.x;   // 4096 total (grid 16)
    int e = idx >> 6, f = idx & 63;
    float s = 0.f;
#pragma unroll 8
    for (int d = 0; d < 64; ++d) s = fmaf(Wq[d * 64 + e], Wk[d * 64 + f], s);
    M[idx] = s * (1.0f / 32.0f);
    Wvb[idx] = f2bf(Wv[idx]);
}

// ---------------------------------------------------------------------------
// K0b: Wo (1024x1024 f32) -> bf16
// ---------------------------------------------------------------------------
__global__ __launch_bounds__(256) void k_cw(const float4* __restrict__ Wo4,
                                            ushort4* __restrict__ Wob4) {
    int idx = blockIdx.x * 256 + threadIdx.x;   // 262144 (grid 1024)
    float4 v = Wo4[idx];
    ushort4 o;
    o.x = f2bf(v.x); o.y = f2bf(v.y); o.z = f2bf(v.z); o.w = f2bf(v.w);
    Wob4[idx] = o;
}

// ---------------------------------------------------------------------------
// K1a: planar bf16 key gather: kbp[nh][l][f] = bf16(keys[n, l, h*64+f])
// ---------------------------------------------------------------------------
__global__ __launch_bounds__(256) void k_kb(const float* __restrict__ keys,
                                            unsigned short* __restrict__ kbp) {
    const int tid  = threadIdx.x;
    const int b    = blockIdx.x;          // 1024
    const int tile = b & 15;
    const int nh   = b >> 4;
    const int h    = nh & 15;
    const int n    = nh >> 4;
    const int t0   = tile * 64;

    const float* kbase = keys + ((size_t)(n * 1024 + t0)) * 1024 + h * 64;
    unsigned short* kout = kbp + ((size_t)(nh * 1024 + t0)) * 64;
#pragma unroll
    for (int i = 0; i < 4; ++i) {
        int idx = tid + i * 256;          // 1024 float4s
        int r = idx >> 4, f0 = (idx & 15) * 4;
        float4 kv = *reinterpret_cast<const float4*>(kbase + (size_t)r * 1024 + f0);
        ushort4 ko; ko.x = f2bf(kv.x); ko.y = f2bf(kv.y);
        ko.z = f2bf(kv.z); ko.w = f2bf(kv.w);
        *reinterpret_cast<ushort4*>(kout + (size_t)r * 64 + f0) = ko;
    }
}

// ---------------------------------------------------------------------------
// K1b (fused): per (nh, 64-row tile):
//   phase A: yq = xq @ M via MFMA (yq only in LDS, C->A relayout via LDS)
//   phase B: energy 64x192 via MFMA (B-frags from planar bf16 keys in global),
//            banded softmax row-normalize, column sums -> w[n,h,l] atomics.
// ---------------------------------------------------------------------------
__global__ __launch_bounds__(256) void k_w2f(const float* __restrict__ query,
                                             const unsigned short* __restrict__ kbp,
                                             const float* __restrict__ Mm,
                                             float* __restrict__ w) {
    __shared__ unsigned short xqA[64 * 72];   // [r][e] bf16, stride 72
    __shared__ unsigned short Mt[64 * 72];    // [f][e] = M[e][f]
    __shared__ unsigned short yqA[64 * 72];   // [r][f] bf16
    __shared__ float wloc[192];

    const int tid  = threadIdx.x;
    const int b    = blockIdx.x;          // 1024
    const int tile = b & 15;
    const int nh   = b >> 4;
    const int h    = nh & 15;
    const int n    = nh >> 4;
    const int t0   = tile * 64;

    if (tid < 192) wloc[tid] = 0.f;

    // stage Mt[f][e] = bf16(M[e][f])
    for (int idx = tid; idx < 4096; idx += 256) {
        int e = idx >> 6, f = idx & 63;
        Mt[f * 72 + e] = f2bf(Mm[idx]);
    }
    // stage xqA[r][e] = bf16(query[n, t0+r, h*64+e])
    {
        const float* qbase = query + ((size_t)(n * 1024 + t0)) * 1024 + h * 64;
#pragma unroll
        for (int i = 0; i < 4; ++i) {
            int idx = tid + i * 256;
            int r = idx >> 4, f0 = (idx & 15) * 4;
            float4 qv = *reinterpret_cast<const float4*>(qbase + (size_t)r * 1024 + f0);
            ushort4 qo; qo.x = f2bf(qv.x); qo.y = f2bf(qv.y);
            qo.z = f2bf(qv.z); qo.w = f2bf(qv.w);
            *reinterpret_cast<ushort4*>(&xqA[r * 72 + f0]) = qo;
        }
    }
    __syncthreads();

    const int wv = tid >> 6, lane = tid & 63;
    const int m = lane & 15, q4 = lane >> 4, ksel = q4 * 8;

    // ---- phase A: yq rows wv*16..+15 ----
    {
        short8 af[2];
#pragma unroll
        for (int ch = 0; ch < 2; ++ch)
            af[ch] = *reinterpret_cast<const short8*>(
                &xqA[(wv * 16 + m) * 72 + ch * 32 + ksel]);
        f32x4 acc[4];
#pragma unroll
        for (int fc = 0; fc < 4; ++fc) {
            acc[fc] = f32x4{0.f, 0.f, 0.f, 0.f};
#pragma unroll
            for (int ch = 0; ch < 2; ++ch) {
                short8 bf = *reinterpret_cast<const short8*>(
                    &Mt[(fc * 16 + m) * 72 + ch * 32 + ksel]);
                acc[fc] = __builtin_amdgcn_mfma_f32_16x16x32_bf16(af[ch], bf, acc[fc], 0, 0, 0);
            }
        }
        // C layout (col=lane&15, row=q4*4+reg) -> A-layout LDS tile
#pragma unroll
        for (int fc = 0; fc < 4; ++fc)
#pragma unroll
            for (int r = 0; r < 4; ++r)
                yqA[(wv * 16 + q4 * 4 + r) * 72 + fc * 16 + m] = f2bf(acc[fc][r]);
    }
    __syncthreads();

    // ---- phase B: energy rows wv*16..+15 x 192 keys ----
    const unsigned short* ya = &yqA[(wv * 16 + m) * 72];
    short8 af0 = *reinterpret_cast<const short8*>(ya + ksel);
    short8 af1 = *reinterpret_cast<const short8*>(ya + 32 + ksel);

    const unsigned short* kb = kbp + (size_t)nh * 1024 * 64;
    short8 bfr[12][2];
#pragma unroll
    for (int ni = 0; ni < 12; ++ni) {
        int l = t0 - 127 + ni * 16 + m;
        int lc = min(max(l, 0), 1023);
        const unsigned short* kp = kb + (size_t)lc * 64 + ksel;
        bfr[ni][0] = *reinterpret_cast<const short8*>(kp);
        bfr[ni][1] = *reinterpret_cast<const short8*>(kp + 32);
    }

    f32x4 acc[12];
#pragma unroll
    for (int ni = 0; ni < 12; ++ni) {
        acc[ni] = f32x4{0.f, 0.f, 0.f, 0.f};
        acc[ni] = __builtin_amdgcn_mfma_f32_16x16x32_bf16(af0, bfr[ni][0], acc[ni], 0, 0, 0);
        acc[ni] = __builtin_amdgcn_mfma_f32_16x16x32_bf16(af1, bfr[ni][1], acc[ni], 0, 0, 0);
    }

    // banded softmax: col c = ni*16+m, row = wv*16 + q4*4 + reg (local)
    const int rbase = wv * 16 + q4 * 4;
    float rs[4] = {0.f, 0.f, 0.f, 0.f};
#pragma unroll
    for (int ni = 0; ni < 12; ++ni) {
        const int c = ni * 16 + m;
#pragma unroll
        for (int reg = 0; reg < 4; ++reg) {
            const int rlw = rbase + reg;
            bool valid = (c >= rlw) && (c <= rlw + 127) && (c + t0 >= 127);
            float e = valid ? __expf(acc[ni][reg]) : 0.f;
            acc[ni][reg] = e;
            rs[reg] += e;
        }
    }
#pragma unroll
    for (int reg = 0; reg < 4; ++reg) {
#pragma unroll
        for (int mm = 1; mm < 16; mm <<= 1) rs[reg] += __shfl_xor(rs[reg], mm);
        rs[reg] = 1.0f / rs[reg];         // diagonal always valid -> > 0
    }
#pragma unroll
    for (int ni = 0; ni < 12; ++ni) {
        float cs = acc[ni][0] * rs[0] + acc[ni][1] * rs[1] +
                   acc[ni][2] * rs[2] + acc[ni][3] * rs[3];
        cs += __shfl_xor(cs, 16);
        cs += __shfl_xor(cs, 32);
        if (lane < 16) atomicAdd(&wloc[ni * 16 + m], cs);
    }
    __syncthreads();

    for (int c = tid; c < 192; c += 256) {
        int l = t0 - 127 + c;
        if (l >= 0 && l < 1024)
            atomicAdd(&w[(size_t)nh * 1024 + l], wloc[c]);
    }
}

// ---------------------------------------------------------------------------
// K2: apb[row][d] = bf16( w_scale(row) * sum_e values[row][e] * Wv[d][e] )
// MFMA, frags direct from global. values viewed as (65536, 64) row-major.
// ---------------------------------------------------------------------------
__global__ __launch_bounds__(256) void k_ap2(const float* __restrict__ values,
                                             const unsigned short* __restrict__ Wvb,
                                             const float* __restrict__ w,
                                             unsigned short* __restrict__ apb) {
    const int tid = threadIdx.x;
    const long R0 = (long)blockIdx.x * 64;    // 1024 blocks
    const int wv = tid >> 6, lane = tid & 63;
    const int m = lane & 15, ksel = (lane >> 4) * 8;

    const float* va = values + (R0 + wv * 16 + m) * 64;
    short8 af[2];
#pragma unroll
    for (int ch = 0; ch < 2; ++ch) {
        float4 x0 = *reinterpret_cast<const float4*>(va + ch * 32 + ksel);
        float4 x1 = *reinterpret_cast<const float4*>(va + ch * 32 + ksel + 4);
        short8 a;
        a[0] = (short)f2bf(x0.x); a[1] = (short)f2bf(x0.y);
        a[2] = (short)f2bf(x0.z); a[3] = (short)f2bf(x0.w);
        a[4] = (short)f2bf(x1.x); a[5] = (short)f2bf(x1.y);
        a[6] = (short)f2bf(x1.z); a[7] = (short)f2bf(x1.w);
        af[ch] = a;
    }

    f32x4 acc[4];
#pragma unroll
    for (int dc = 0; dc < 4; ++dc) {
        acc[dc] = f32x4{0.f, 0.f, 0.f, 0.f};
#pragma unroll
        for (int ch = 0; ch < 2; ++ch) {
            short8 bf = *reinterpret_cast<const short8*>(
                Wvb + (size_t)(dc * 16 + m) * 64 + ch * 32 + ksel);
            acc[dc] = __builtin_amdgcn_mfma_f32_16x16x32_bf16(af[ch], bf, acc[dc], 0, 0, 0);
        }
    }

    const long rowb = R0 + wv * 16 + (lane >> 4) * 4;
    float wf[4];
#pragma unroll
    for (int reg = 0; reg < 4; ++reg) {
        long rg = rowb + reg;
        int hh = (int)(rg & 15);
        int ll = (int)((rg >> 4) & 1023);
        int nn = (int)(rg >> 14);
        wf[reg] = w[((size_t)(nn * 16 + hh) << 10) + ll];
    }
#pragma unroll
    for (int dc = 0; dc < 4; ++dc)
#pragma unroll
        for (int reg = 0; reg < 4; ++reg)
            apb[(size_t)(rowb + reg) * 64 + dc * 16 + m] = f2bf(acc[dc][reg] * wf[reg]);
}

// ---------------------------------------------------------------------------
// K3: out = ap (4096x1024 bf16) @ Wo^T (bf16) + bo, f32 out. (unchanged)
// ---------------------------------------------------------------------------
__global__ __launch_bounds__(256) void k_out_mfma(
    const unsigned short* __restrict__ apb,
    const unsigned short* __restrict__ wob,
    const float* __restrict__ bo,
    float* __restrict__ out) {
    __shared__ unsigned short As[128 * 32];
    __shared__ unsigned short Bs[128 * 32];

    const int tid  = threadIdx.x;
    const int wv   = tid >> 6;
    const int lane = tid & 63;
    const int wy   = wv >> 1, wx = wv & 1;

    const int bx = blockIdx.x & 7;
    const int by = blockIdx.x >> 3;
    const long arow0 = (long)by * 128;
    const int  bcol0 = bx * 128;

    f32x4 acc[4][4];
#pragma unroll
    for (int mi = 0; mi < 4; ++mi)
#pragma unroll
        for (int ni = 0; ni < 4; ++ni) acc[mi][ni] = f32x4{0.f, 0.f, 0.f, 0.f};

    const int r0s = tid >> 2;
    const int kks = (tid & 3) * 8;

    for (int kt = 0; kt < 32; ++kt) {
        const int k0 = kt * 32;
#pragma unroll
        for (int i = 0; i < 2; ++i) {
            const unsigned short* g =
                apb + (arow0 + i * 64 + r0s) * 1024 + k0 + kks;
            __builtin_amdgcn_global_load_lds(
                (const __attribute__((address_space(1))) unsigned int*)g,
                (__attribute__((address_space(3))) unsigned int*)&As[i * 2048 + wv * 512],
                16, 0, 0);
        }
#pragma unroll
        for (int i = 0; i < 2; ++i) {
            const unsigned short* g =
                wob + (size_t)(bcol0 + i * 64 + r0s) * 1024 + k0 + kks;
            __builtin_amdgcn_global_load_lds(
                (const __attribute__((address_space(1))) unsigned int*)g,
                (__attribute__((address_space(3))) unsigned int*)&Bs[i * 2048 + wv * 512],
                16, 0, 0);
        }
        __syncthreads();

        const int koff = (lane >> 4) * 8;
        const int rA = wy * 64 + (lane & 15);
        const int rB = wx * 64 + (lane & 15);
        short8 af[4], bf[4];
#pragma unroll
        for (int mi = 0; mi < 4; ++mi)
            af[mi] = *reinterpret_cast<const short8*>(&As[(rA + mi * 16) * 32 + koff]);
#pragma unroll
        for (int ni = 0; ni < 4; ++ni)
            bf[ni] = *reinterpret_cast<const short8*>(&Bs[(rB + ni * 16) * 32 + koff]);
#pragma unroll
        for (int mi = 0; mi < 4; ++mi)
#pragma unroll
            for (int ni = 0; ni < 4; ++ni)
                acc[mi][ni] = __builtin_amdgcn_mfma_f32_16x16x32_bf16(
                    af[mi], bf[ni], acc[mi][ni], 0, 0, 0);
        __syncthreads();
    }

    const int colb = bcol0 + wx * 64 + (lane & 15);
    const int rowb = (int)arow0 + wy * 64 + (lane >> 4) * 4;
#pragma unroll
    for (int ni = 0; ni < 4; ++ni) {
        const int col = colb + ni * 16;
        const float bias = bo[col];
#pragma unroll
        for (int mi = 0; mi < 4; ++mi) {
            const int row = rowb + mi * 16;
#pragma unroll
            for (int r = 0; r < 4; ++r)
                out[(size_t)(row + r) * 1024 + col] = acc[mi][ni][r] + bias;
        }
    }
}

// ---------------------------------------------------------------------------
extern "C" void kernel_launch(void* const* d_in, const int* in_sizes, int n_in,
                              void* d_out, int out_size, void* d_ws, size_t ws_size,
                              hipStream_t stream) {
    const float* values = (const float*)d_in[0];
    const float* keys   = (const float*)d_in[1];
    const float* query  = (const float*)d_in[2];
    const float* Wv     = (const float*)d_in[4];
    const float* Wk     = (const float*)d_in[5];
    const float* Wq     = (const float*)d_in[6];
    const float* Wo     = (const float*)d_in[7];
    const float* bo     = (const float*)d_in[8];
    float* out = (float*)d_out;

    // workspace layout (peak 10.77 MB, below round-2-proven footprint):
    float* Mws = (float*)d_ws;                          // 16 KB
    float* w   = Mws + 4096;                            // 256 KB
    unsigned short* Wvb = (unsigned short*)(w + 65536); // 8 KB
    unsigned short* wob = Wvb + 4096;                   // 2 MB
    unsigned short* kbp = wob + 1024 * 1024;            // 8 MB
    unsigned short* apb = kbp;                          // overlay: kbp dead after k_w2f

    hipMemsetAsync(w, 0, 65536 * sizeof(float), stream);
    kM2<<<16, 256, 0, stream>>>(Wq, Wk, Wv, Mws, Wvb);
    k_cw<<<1024, 256, 0, stream>>>((const float4*)Wo, (ushort4*)wob);
    k_kb<<<1024, 256, 0, stream>>>(keys, kbp);
    k_w2f<<<1024, 256, 0, stream>>>(query, kbp, Mws, w);
    k_ap2<<<1024, 256, 0, stream>>>(values, Wvb, w, apb);
    k_out_mfma<<<256, 256, 0, stream>>>(apb, wob, bo, out);
}

// Round 5
// 166.245 us; speedup vs baseline: 2.5955x; 1.0205x over previous
//
#include <hip/hip_runtime.h>
#include <hip/hip_bf16.h>
#include <math.h>

// Problem constants: N=4, L=1024, D=1024, H=16, HD=64, HIST=128, SCALE=32
// Faithful-bug structure: attention[n,l,h,d] = (sum_q scores[n,h,q,l]) * v[n,l,h,d]
// => only column sums w[n,h,l] of softmax needed.
// Energy trick: q_p . k_p = xq^T (Wq^T Wk / 32) xk, M = Wq^T Wk / 32 (64x64).
// Round 5: collapse 7 dispatches -> 4 (k_prep fuses M/Wo-cast/key-gather/w-zero);
// k_w2 loads query & M frags direct to registers (LDS 28.5KB -> 9.6KB).
// r3 failure root cause was kbp/yqp overlay overlap (ws is 256MB, no overflow).

using short8 = __attribute__((ext_vector_type(8))) short;
using f32x4  = __attribute__((ext_vector_type(4))) float;

__device__ __forceinline__ unsigned short f2bf(float x) {
    unsigned u = __float_as_uint(x);
    u += 0x7FFFu + ((u >> 16) & 1u);      // round-to-nearest-even
    return (unsigned short)(u >> 16);
}

// ---------------------------------------------------------------------------
// K0 (fused prep), grid 2064:
//  blocks 0..1023   : kbp[nh][l][f] = bf16(keys[n,l,h*64+f]); zero w
//  blocks 1024..2047: wob = bf16(Wo)
//  blocks 2048..2063: Mtb[f][e] = bf16((Wq^T Wk /32)[e][f]); Wvb = bf16(Wv)
// ---------------------------------------------------------------------------
__global__ __launch_bounds__(256) void k_prep(const float* __restrict__ keys,
                                              const float* __restrict__ Wq,
                                              const float* __restrict__ Wk,
                                              const float* __restrict__ Wv,
                                              const float4* __restrict__ Wo4,
                                              unsigned short* __restrict__ kbp,
                                              float* __restrict__ w,
                                              ushort4* __restrict__ wob4,
                                              unsigned short* __restrict__ Mtb,
                                              unsigned short* __restrict__ Wvb) {
    const int b = blockIdx.x, tid = threadIdx.x;
    if (b < 1024) {
        const int tile = b & 15, nh = b >> 4, h = nh & 15, n = nh >> 4;
        const int t0 = tile * 64;
        const float* kbase = keys + ((size_t)(n * 1024 + t0)) * 1024 + h * 64;
        unsigned short* kout = kbp + ((size_t)(nh * 1024 + t0)) * 64;
#pragma unroll
        for (int i = 0; i < 4; ++i) {
            int idx = tid + i * 256;          // 1024 float4s
            int r = idx >> 4, f0 = (idx & 15) * 4;
            float4 kv = *reinterpret_cast<const float4*>(kbase + (size_t)r * 1024 + f0);
            ushort4 ko; ko.x = f2bf(kv.x); ko.y = f2bf(kv.y);
            ko.z = f2bf(kv.z); ko.w = f2bf(kv.w);
            *reinterpret_cast<ushort4*>(kout + (size_t)r * 64 + f0) = ko;
        }
        if (tid < 64) w[b * 64 + tid] = 0.f;
    } else if (b < 2048) {
        int idx = (b - 1024) * 256 + tid;     // 262144 float4s
        float4 v = Wo4[idx];
        ushort4 o; o.x = f2bf(v.x); o.y = f2bf(v.y);
        o.z = f2bf(v.z); o.w = f2bf(v.w);
        wob4[idx] = o;
    } else {
        int idx = (b - 2048) * 256 + tid;     // 4096
        int e = idx >> 6, f = idx & 63;
        float s = 0.f;
#pragma unroll 8
        for (int d = 0; d < 64; ++d) s = fmaf(Wq[d * 64 + e], Wk[d * 64 + f], s);
        Mtb[f * 64 + e] = f2bf(s * (1.0f / 32.0f));   // planar [f][e] for B-frags
        Wvb[idx] = f2bf(Wv[idx]);
    }
}

// ---------------------------------------------------------------------------
// K1: per (nh, 64-row tile):
//  phase A: yq = xq @ M via MFMA; A-frags direct from query f32, B-frags direct
//           from Mtb bf16 global; C->A relayout via small LDS tile.
//  phase B: energy 64x192 MFMA (B-frags from planar kbp), banded softmax,
//           column sums -> w atomics.
// ---------------------------------------------------------------------------
__global__ __launch_bounds__(256) void k_w2(const float* __restrict__ query,
                                            const unsigned short* __restrict__ kbp,
                                            const unsigned short* __restrict__ Mtb,
                                            float* __restrict__ w) {
    __shared__ unsigned short yqA[64 * 72];   // [r][f] bf16, stride 72
    __shared__ float wloc[192];

    const int tid  = threadIdx.x;
    const int b    = blockIdx.x;          // 1024
    const int tile = b & 15;
    const int nh   = b >> 4;
    const int h    = nh & 15;
    const int n    = nh >> 4;
    const int t0   = tile * 64;

    if (tid < 192) wloc[tid] = 0.f;

    const int wv = tid >> 6, lane = tid & 63;
    const int m = lane & 15, q4 = lane >> 4, ksel = q4 * 8;

    // ---- phase A ----
    {
        const float* qrow = query + ((size_t)(n * 1024 + t0 + wv * 16 + m)) * 1024 + h * 64;
        short8 af[2];
#pragma unroll
        for (int ch = 0; ch < 2; ++ch) {
            float4 x0 = *reinterpret_cast<const float4*>(qrow + ch * 32 + ksel);
            float4 x1 = *reinterpret_cast<const float4*>(qrow + ch * 32 + ksel + 4);
            short8 a;
            a[0] = (short)f2bf(x0.x); a[1] = (short)f2bf(x0.y);
            a[2] = (short)f2bf(x0.z); a[3] = (short)f2bf(x0.w);
            a[4] = (short)f2bf(x1.x); a[5] = (short)f2bf(x1.y);
            a[6] = (short)f2bf(x1.z); a[7] = (short)f2bf(x1.w);
            af[ch] = a;
        }
        f32x4 acc[4];
#pragma unroll
        for (int fc = 0; fc < 4; ++fc) {
            acc[fc] = f32x4{0.f, 0.f, 0.f, 0.f};
#pragma unroll
            for (int ch = 0; ch < 2; ++ch) {
                short8 bf = *reinterpret_cast<const short8*>(
                    Mtb + (size_t)(fc * 16 + m) * 64 + ch * 32 + ksel);
                acc[fc] = __builtin_amdgcn_mfma_f32_16x16x32_bf16(af[ch], bf, acc[fc], 0, 0, 0);
            }
        }
        // C layout (col=m, row=q4*4+reg) -> A-layout LDS tile
#pragma unroll
        for (int fc = 0; fc < 4; ++fc)
#pragma unroll
            for (int r = 0; r < 4; ++r)
                yqA[(wv * 16 + q4 * 4 + r) * 72 + fc * 16 + m] = f2bf(acc[fc][r]);
    }
    __syncthreads();

    // ---- phase B ----
    const unsigned short* ya = &yqA[(wv * 16 + m) * 72];
    short8 af0 = *reinterpret_cast<const short8*>(ya + ksel);
    short8 af1 = *reinterpret_cast<const short8*>(ya + 32 + ksel);

    const unsigned short* kb = kbp + (size_t)nh * 1024 * 64;
    short8 bfr[12][2];
#pragma unroll
    for (int ni = 0; ni < 12; ++ni) {
        int l = t0 - 127 + ni * 16 + m;
        int lc = min(max(l, 0), 1023);
        const unsigned short* kp = kb + (size_t)lc * 64 + ksel;
        bfr[ni][0] = *reinterpret_cast<const short8*>(kp);
        bfr[ni][1] = *reinterpret_cast<const short8*>(kp + 32);
    }

    f32x4 acc[12];
#pragma unroll
    for (int ni = 0; ni < 12; ++ni) {
        acc[ni] = f32x4{0.f, 0.f, 0.f, 0.f};
        acc[ni] = __builtin_amdgcn_mfma_f32_16x16x32_bf16(af0, bfr[ni][0], acc[ni], 0, 0, 0);
        acc[ni] = __builtin_amdgcn_mfma_f32_16x16x32_bf16(af1, bfr[ni][1], acc[ni], 0, 0, 0);
    }

    // banded softmax: col c = ni*16+m, local row = wv*16 + q4*4 + reg
    const int rbase = wv * 16 + q4 * 4;
    float rs[4] = {0.f, 0.f, 0.f, 0.f};
#pragma unroll
    for (int ni = 0; ni < 12; ++ni) {
        const int c = ni * 16 + m;
#pragma unroll
        for (int reg = 0; reg < 4; ++reg) {
            const int rlw = rbase + reg;
            bool valid = (c >= rlw) && (c <= rlw + 127) && (c + t0 >= 127);
            float e = valid ? __expf(acc[ni][reg]) : 0.f;
            acc[ni][reg] = e;
            rs[reg] += e;
        }
    }
#pragma unroll
    for (int reg = 0; reg < 4; ++reg) {
#pragma unroll
        for (int mm = 1; mm < 16; mm <<= 1) rs[reg] += __shfl_xor(rs[reg], mm);
        rs[reg] = 1.0f / rs[reg];         // diagonal always valid -> > 0
    }
#pragma unroll
    for (int ni = 0; ni < 12; ++ni) {
        float cs = acc[ni][0] * rs[0] + acc[ni][1] * rs[1] +
                   acc[ni][2] * rs[2] + acc[ni][3] * rs[3];
        cs += __shfl_xor(cs, 16);
        cs += __shfl_xor(cs, 32);
        if (lane < 16) atomicAdd(&wloc[ni * 16 + m], cs);
    }
    __syncthreads();

    for (int c = tid; c < 192; c += 256) {
        int l = t0 - 127 + c;
        if (l >= 0 && l < 1024)
            atomicAdd(&w[(size_t)nh * 1024 + l], wloc[c]);
    }
}

// ---------------------------------------------------------------------------
// K2: apb[row][d] = bf16( w_scale(row) * sum_e values[row][e] * Wv[d][e] )
// MFMA, frags direct from global. values viewed as (65536, 64) row-major.
// ---------------------------------------------------------------------------
__global__ __launch_bounds__(256) void k_ap2(const float* __restrict__ values,
                                             const unsigned short* __restrict__ Wvb,
                                             const float* __restrict__ w,
                                             unsigned short* __restrict__ apb) {
    const int tid = threadIdx.x;
    const long R0 = (long)blockIdx.x * 64;    // 1024 blocks
    const int wv = tid >> 6, lane = tid & 63;
    const int m = lane & 15, ksel = (lane >> 4) * 8;

    const float* va = values + (R0 + wv * 16 + m) * 64;
    short8 af[2];
#pragma unroll
    for (int ch = 0; ch < 2; ++ch) {
        float4 x0 = *reinterpret_cast<const float4*>(va + ch * 32 + ksel);
        float4 x1 = *reinterpret_cast<const float4*>(va + ch * 32 + ksel + 4);
        short8 a;
        a[0] = (short)f2bf(x0.x); a[1] = (short)f2bf(x0.y);
        a[2] = (short)f2bf(x0.z); a[3] = (short)f2bf(x0.w);
        a[4] = (short)f2bf(x1.x); a[5] = (short)f2bf(x1.y);
        a[6] = (short)f2bf(x1.z); a[7] = (short)f2bf(x1.w);
        af[ch] = a;
    }

    f32x4 acc[4];
#pragma unroll
    for (int dc = 0; dc < 4; ++dc) {
        acc[dc] = f32x4{0.f, 0.f, 0.f, 0.f};
#pragma unroll
        for (int ch = 0; ch < 2; ++ch) {
            short8 bf = *reinterpret_cast<const short8*>(
                Wvb + (size_t)(dc * 16 + m) * 64 + ch * 32 + ksel);
            acc[dc] = __builtin_amdgcn_mfma_f32_16x16x32_bf16(af[ch], bf, acc[dc], 0, 0, 0);
        }
    }

    const long rowb = R0 + wv * 16 + (lane >> 4) * 4;
    float wf[4];
#pragma unroll
    for (int reg = 0; reg < 4; ++reg) {
        long rg = rowb + reg;
        int hh = (int)(rg & 15);
        int ll = (int)((rg >> 4) & 1023);
        int nn = (int)(rg >> 14);
        wf[reg] = w[((size_t)(nn * 16 + hh) << 10) + ll];
    }
#pragma unroll
    for (int dc = 0; dc < 4; ++dc)
#pragma unroll
        for (int reg = 0; reg < 4; ++reg)
            apb[(size_t)(rowb + reg) * 64 + dc * 16 + m] = f2bf(acc[dc][reg] * wf[reg]);
}

// ---------------------------------------------------------------------------
// K3: out = ap (4096x1024 bf16) @ Wo^T (bf16) + bo, f32 out.
// ---------------------------------------------------------------------------
__global__ __launch_bounds__(256) void k_out_mfma(
    const unsigned short* __restrict__ apb,
    const unsigned short* __restrict__ wob,
    const float* __restrict__ bo,
    float* __restrict__ out) {
    __shared__ unsigned short As[128 * 32];
    __shared__ unsigned short Bs[128 * 32];

    const int tid  = threadIdx.x;
    const int wv   = tid >> 6;
    const int lane = tid & 63;
    const int wy   = wv >> 1, wx = wv & 1;

    const int bx = blockIdx.x & 7;
    const int by = blockIdx.x >> 3;
    const long arow0 = (long)by * 128;
    const int  bcol0 = bx * 128;

    f32x4 acc[4][4];
#pragma unroll
    for (int mi = 0; mi < 4; ++mi)
#pragma unroll
        for (int ni = 0; ni < 4; ++ni) acc[mi][ni] = f32x4{0.f, 0.f, 0.f, 0.f};

    const int r0s = tid >> 2;
    const int kks = (tid & 3) * 8;

    for (int kt = 0; kt < 32; ++kt) {
        const int k0 = kt * 32;
#pragma unroll
        for (int i = 0; i < 2; ++i) {
            const unsigned short* g =
                apb + (arow0 + i * 64 + r0s) * 1024 + k0 + kks;
            __builtin_amdgcn_global_load_lds(
                (const __attribute__((address_space(1))) unsigned int*)g,
                (__attribute__((address_space(3))) unsigned int*)&As[i * 2048 + wv * 512],
                16, 0, 0);
        }
#pragma unroll
        for (int i = 0; i < 2; ++i) {
            const unsigned short* g =
                wob + (size_t)(bcol0 + i * 64 + r0s) * 1024 + k0 + kks;
            __builtin_amdgcn_global_load_lds(
                (const __attribute__((address_space(1))) unsigned int*)g,
                (__attribute__((address_space(3))) unsigned int*)&Bs[i * 2048 + wv * 512],
                16, 0, 0);
        }
        __syncthreads();

        const int koff = (lane >> 4) * 8;
        const int rA = wy * 64 + (lane & 15);
        const int rB = wx * 64 + (lane & 15);
        short8 af[4], bf[4];
#pragma unroll
        for (int mi = 0; mi < 4; ++mi)
            af[mi] = *reinterpret_cast<const short8*>(&As[(rA + mi * 16) * 32 + koff]);
#pragma unroll
        for (int ni = 0; ni < 4; ++ni)
            bf[ni] = *reinterpret_cast<const short8*>(&Bs[(rB + ni * 16) * 32 + koff]);
#pragma unroll
        for (int mi = 0; mi < 4; ++mi)
#pragma unroll
            for (int ni = 0; ni < 4; ++ni)
                acc[mi][ni] = __builtin_amdgcn_mfma_f32_16x16x32_bf16(
                    af[mi], bf[ni], acc[mi][ni], 0, 0, 0);
        __syncthreads();
    }

    const int colb = bcol0 + wx * 64 + (lane & 15);
    const int rowb = (int)arow0 + wy * 64 + (lane >> 4) * 4;
#pragma unroll
    for (int ni = 0; ni < 4; ++ni) {
        const int col = colb + ni * 16;
        const float bias = bo[col];
#pragma unroll
        for (int mi = 0; mi < 4; ++mi) {
            const int row = rowb + mi * 16;
#pragma unroll
            for (int r = 0; r < 4; ++r)
                out[(size_t)(row + r) * 1024 + col] = acc[mi][ni][r] + bias;
        }
    }
}

// ---------------------------------------------------------------------------
extern "C" void kernel_launch(void* const* d_in, const int* in_sizes, int n_in,
                              void* d_out, int out_size, void* d_ws, size_t ws_size,
                              hipStream_t stream) {
    const float* values = (const float*)d_in[0];
    const float* keys   = (const float*)d_in[1];
    const float* query  = (const float*)d_in[2];
    const float* Wv     = (const float*)d_in[4];
    const float* Wk     = (const float*)d_in[5];
    const float* Wq     = (const float*)d_in[6];
    const float* Wo     = (const float*)d_in[7];
    const float* bo     = (const float*)d_in[8];
    float* out = (float*)d_out;

    // workspace layout (~18.3 MB; ws is 256 MiB — no overlays, r3 lesson):
    float* w            = (float*)d_ws;                 // 65536 f32   (256 KB)
    unsigned short* Mtb = (unsigned short*)(w + 65536); // 4096 bf16   (8 KB)
    unsigned short* Wvb = Mtb + 4096;                   // 4096 bf16   (8 KB)
    unsigned short* wob = Wvb + 4096;                   // 1M bf16     (2 MB)
    unsigned short* kbp = wob + 1024 * 1024;            // 4M bf16     (8 MB)
    unsigned short* apb = kbp + 64 * 1024 * 64;         // 4M bf16     (8 MB)

    k_prep<<<2064, 256, 0, stream>>>(keys, Wq, Wk, Wv, (const float4*)Wo,
                                     kbp, w, (ushort4*)wob, Mtb, Wvb);
    k_w2<<<1024, 256, 0, stream>>>(query, kbp, Mtb, w);
    k_ap2<<<1024, 256, 0, stream>>>(values, Wvb, w, apb);
    k_out_mfma<<<256, 256, 0, stream>>>(apb, wob, bo, out);
}